// Round 1
// baseline (179.847 us; speedup 1.0000x reference)
//
#include <hip/hip_runtime.h>

// Shapes from reference: B=4, S_PAST=4096, S_NEW=16, H=32, D=128, float32.
// k_out/v_out: [B, 4112, 32, 128]; d_out = k_out flat ++ v_out flat.
constexpr int  B          = 4;
constexpr int  S_PAST     = 4096;
constexpr int  S_NEW      = 16;
constexpr int  S_OUT      = S_PAST + S_NEW;          // 4112
constexpr int  ROW_F4     = (32 * 128) / 4;          // 1024 float4 per (b,s) row
constexpr long PER_BATCH  = (long)S_OUT * ROW_F4;    // 4,210,688 float4
constexpr long OUT_HALF   = (long)B * PER_BATCH;     // 16,842,752 float4 per tensor

__global__ __launch_bounds__(256)
void kv_append_kernel(const float4* __restrict__ k_cache,
                      const float4* __restrict__ v_cache,
                      const float4* __restrict__ k_new,
                      const float4* __restrict__ v_new,
                      float4* __restrict__ out)
{
    const long idx   = (long)blockIdx.x * blockDim.x + threadIdx.x; // float4 idx within batch
    const int  b     = blockIdx.y;
    const int  which = blockIdx.z;   // 0 = k, 1 = v

    // ROW_F4 = 1024 -> shifts, no divides.
    const int s   = (int)(idx >> 10);
    const int col = (int)(idx & 1023);

    const float4* __restrict__ cache = which ? v_cache : k_cache;
    const float4* __restrict__ fresh = which ? v_new   : k_new;

    float4 val;
    if (s < S_PAST) {
        val = cache[((long)b * S_PAST + s) * ROW_F4 + col];
    } else {
        val = fresh[((long)b * S_NEW + (s - S_PAST)) * ROW_F4 + col];
    }
    out[(long)which * OUT_HALF + (long)b * PER_BATCH + idx] = val;
}

extern "C" void kernel_launch(void* const* d_in, const int* in_sizes, int n_in,
                              void* d_out, int out_size, void* d_ws, size_t ws_size,
                              hipStream_t stream)
{
    const float4* k_cache = (const float4*)d_in[0];
    const float4* v_cache = (const float4*)d_in[1];
    const float4* k_new   = (const float4*)d_in[2];
    const float4* v_new   = (const float4*)d_in[3];
    float4*       out     = (float4*)d_out;

    // PER_BATCH = 4,210,688 = 16,448 * 256 exactly -> no tail.
    dim3 grid(PER_BATCH / 256, B, 2);
    dim3 block(256, 1, 1);
    kv_append_kernel<<<grid, block, 0, stream>>>(k_cache, v_cache, k_new, v_new, out);
}